// Round 8
// baseline (2797.801 us; speedup 1.0000x reference)
//
#include <hip/hip_runtime.h>
#include <hip/hip_bf16.h>

typedef __attribute__((ext_vector_type(8))) short bf16x8;
typedef __attribute__((ext_vector_type(4))) float f32x4;
typedef unsigned short u16;
typedef unsigned int u32;
typedef unsigned long long u64;

__device__ __forceinline__ u16 f2bf(float f) {
  union { float f; unsigned u; } v; v.f = f;
  unsigned r = v.u + 0x7FFFu + ((v.u >> 16) & 1u);   // RTNE
  return (u16)(r >> 16);
}

__device__ __forceinline__ float sigm_fast(float x) {
  return __builtin_amdgcn_rcpf(1.f + __expf(-x));
}
__device__ __forceinline__ float tanh_fast(float x) {
  x = fminf(fmaxf(x, -15.f), 15.f);
  float e = __expf(2.f * x);
  return (e - 1.f) * __builtin_amdgcn_rcpf(e + 1.f);
}

// coherent (LLC) 16B load, untracked by compiler -> caller must waitcnt
__device__ __forceinline__ void ld_llc_b128(const u16* p, bf16x8& r) {
  asm volatile("global_load_dwordx4 %0, %1, off sc0 sc1"
               : "=&v"(r) : "v"(p));
}
// coherent (LLC) 4B store, untracked -> caller must waitcnt before barrier
__device__ __forceinline__ void st_llc_b32(u32* p, u32 v) {
  asm volatile("global_store_dword %0, %1, off sc0 sc1"
               :: "v"(p), "v"(v) : "memory");
}

// ---------------------------------------------------------------------------
// fold (all 4 gates in one dispatch, z = gate):
// Wt[(j*4+g)][k] = sum_m P[m][j] * (W[k][m] * cos(rx[m]))   (bf16 out)
// ---------------------------------------------------------------------------
__global__ __launch_bounds__(256) void fold_kernel(
    const float* __restrict__ W0, const float* __restrict__ rx0, const float* __restrict__ P0,
    const float* __restrict__ W1, const float* __restrict__ rx1, const float* __restrict__ P1,
    const float* __restrict__ W2, const float* __restrict__ rx2, const float* __restrict__ P2,
    const float* __restrict__ W3, const float* __restrict__ rx3, const float* __restrict__ P3,
    u16* __restrict__ Wt)
{
  const int g = blockIdx.z;
  const float* W  = (g == 0) ? W0  : (g == 1) ? W1  : (g == 2) ? W2  : W3;
  const float* rx = (g == 0) ? rx0 : (g == 1) ? rx1 : (g == 2) ? rx2 : rx3;
  const float* P  = (g == 0) ? P0  : (g == 1) ? P1  : (g == 2) ? P2  : P3;
  __shared__ __align__(16) float As[16][68];   // As[m][j]
  __shared__ __align__(16) float Bs[16][68];   // Bs[m][k]
  const int bk = blockIdx.x;   // k-tile 0..15
  const int bj = blockIdx.y;   // j-tile 0..7
  const int tid = threadIdx.x;
  const int tx = tid & 15;     // k-dir
  const int ty = tid >> 4;     // j-dir
  const int j0 = bj * 64, k0 = bk * 64;
  float acc[4][4] = {};
  for (int m0 = 0; m0 < 512; m0 += 16) {
#pragma unroll
    for (int l = 0; l < 4; ++l) {
      int lin = tid + 256 * l;                 // 0..1023
      int mm = lin >> 6, jr = lin & 63;
      As[mm][jr] = P[(m0 + mm) * 512 + j0 + jr];
      int kk = lin >> 4, mb = lin & 15;
      Bs[mb][kk] = W[(k0 + kk) * 512 + m0 + mb] * cosf(rx[m0 + mb]);
    }
    __syncthreads();
#pragma unroll
    for (int mm = 0; mm < 16; ++mm) {
      f32x4 a = *(const f32x4*)&As[mm][ty * 4];
      f32x4 b = *(const f32x4*)&Bs[mm][tx * 4];
#pragma unroll
      for (int i = 0; i < 4; ++i)
#pragma unroll
        for (int jj = 0; jj < 4; ++jj)
          acc[i][jj] += a[i] * b[jj];
    }
    __syncthreads();
  }
#pragma unroll
  for (int i = 0; i < 4; ++i) {
    int j = j0 + ty * 4 + i;
    size_t n = (size_t)(j * 4 + g);
    ushort4 w;
    w.x = f2bf(acc[i][0]); w.y = f2bf(acc[i][1]);
    w.z = f2bf(acc[i][2]); w.w = f2bf(acc[i][3]);
    *(ushort4*)(Wt + n * 1024 + k0 + tx * 4) = w;
  }
}

// bpn[j*4+g] = sum_m b[m]*cos(rx[m])*P[m][j]; grid 32 = 4 gates x 8 j-blocks
__global__ __launch_bounds__(256) void fold_bias(
    const float* __restrict__ b0, const float* __restrict__ rx0, const float* __restrict__ P0,
    const float* __restrict__ b1, const float* __restrict__ rx1, const float* __restrict__ P1,
    const float* __restrict__ b2, const float* __restrict__ rx2, const float* __restrict__ P2,
    const float* __restrict__ b3, const float* __restrict__ rx3, const float* __restrict__ P3,
    float* __restrict__ bpn)
{
  const int g = blockIdx.x >> 3, jb = blockIdx.x & 7;
  const float* b  = (g == 0) ? b0  : (g == 1) ? b1  : (g == 2) ? b2  : b3;
  const float* rx = (g == 0) ? rx0 : (g == 1) ? rx1 : (g == 2) ? rx2 : rx3;
  const float* P  = (g == 0) ? P0  : (g == 1) ? P1  : (g == 2) ? P2  : P3;
  __shared__ float bc[512];
  __shared__ float red[4][65];
  const int tid = threadIdx.x;
  bc[tid] = b[tid] * cosf(rx[tid]);
  bc[tid + 256] = b[tid + 256] * cosf(rx[tid + 256]);
  __syncthreads();
  const int jl = tid & 63, msub = tid >> 6;
  const int j = jb * 64 + jl;
  float acc = 0.f;
  for (int m = msub * 128; m < msub * 128 + 128; ++m)
    acc += bc[m] * P[m * 512 + j];
  red[msub][jl] = acc;
  __syncthreads();
  if (msub == 0)
    bpn[j * 4 + g] = red[0][jl] + red[1][jl] + red[2][jl] + red[3][jl];
}

// convert whole input X (T*B*D f32) to bf16 once
__global__ __launch_bounds__(256) void xcvt_kernel(
    const float* __restrict__ x, u16* __restrict__ xb)
{
  size_t i = (size_t)blockIdx.x * 256 + threadIdx.x;  // group of 4 elems
  f32x4 v = *(const f32x4*)(x + i * 4);
  ushort4 w;
  w.x = f2bf(v[0]); w.y = f2bf(v[1]); w.z = f2bf(v[2]); w.w = f2bf(v[3]);
  *(ushort4*)(xb + i * 4) = w;
}

// zero hbuf (both parities) + cbuf + flags, every launch (replay determinism)
__global__ __launch_bounds__(256) void init_kernel(unsigned* hbuf32, float* cbuf,
                                                   unsigned* flags) {
  int i = blockIdx.x * 256 + threadIdx.x;      // 65536
  hbuf32[i] = 0;
  cbuf[i] = 0.f;
  if (i < 256) flags[i] = 0;
}

__global__ __launch_bounds__(256) void tail_kernel(
    const float* __restrict__ hlast, const float* __restrict__ c,
    float* __restrict__ hx, float* __restrict__ cx)
{
  int i = blockIdx.x * 256 + threadIdx.x;      // 65536
  hx[i] = hlast[i];
  cx[i] = c[i];
}

// ---------------------------------------------------------------------------
// fallback single-step kernel (R1-proven)
// ---------------------------------------------------------------------------
__global__ __launch_bounds__(256) void step_kernel(
    const u16* __restrict__ xb_t, const u16* __restrict__ h_in,
    u16* __restrict__ h_out, const u16* __restrict__ Wt,
    const float* __restrict__ bpn, float* __restrict__ cbuf,
    float* __restrict__ out_t)
{
  __shared__ float pre_s[32][33];
  const int bid = blockIdx.x;
  const int mb = bid >> 6, nb = bid & 63;
  const int b0 = mb * 32, n0 = nb * 32;
  const int tid = threadIdx.x;
  const int wv = tid >> 6, lane = tid & 63;
  const int rt = wv >> 1, nt = wv & 1;
  const int l15 = lane & 15, kg = lane >> 4;
  const int brow = b0 + rt * 16 + l15;
  const int ncol = n0 + nt * 16 + l15;
  const u16* wrow = Wt + (size_t)ncol * 1024;
  const u16* xrow = xb_t + (size_t)brow * 512;
  const u16* hrow = h_in + (size_t)brow * 512;
  f32x4 acc = {0.f, 0.f, 0.f, 0.f};
#pragma unroll 8
  for (int kk = 0; kk < 32; ++kk) {
    const int kb = kk * 32 + kg * 8;
    bf16x8 bfrag = *(const bf16x8*)(wrow + kb);
    bf16x8 afrag;
    if (kb < 512) afrag = *(const bf16x8*)(xrow + kb);
    else          afrag = *(const bf16x8*)(hrow + (kb - 512));
    acc = __builtin_amdgcn_mfma_f32_16x16x32_bf16(afrag, bfrag, acc, 0, 0, 0);
  }
  const float bias = bpn[ncol];
#pragma unroll
  for (int q = 0; q < 4; ++q)
    pre_s[rt * 16 + kg * 4 + q][nt * 16 + l15] = acc[q] + bias;
  __syncthreads();
  const int bb = tid >> 3, jo = tid & 7;
  float pf = pre_s[bb][jo * 4 + 0];
  float pi = pre_s[bb][jo * 4 + 1];
  float pu = pre_s[bb][jo * 4 + 2];
  float po = pre_s[bb][jo * 4 + 3];
  float fg = 1.f / (1.f + __expf(-pf));
  float ig = 1.f / (1.f + __expf(-pi));
  float gg = tanhf(pu);
  float og = 1.f / (1.f + __expf(-po));
  size_t idx = (size_t)(b0 + bb) * 512 + (size_t)(nb * 8 + jo);
  float cv = fg * cbuf[idx] + ig * gg;
  cbuf[idx] = cv;
  float hv = og * tanhf(cv);
  out_t[idx] = hv;
  h_out[idx] = f2bf(hv);
}

// ---------------------------------------------------------------------------
// persistent recurrence v3: 128 wgs, each owns TWO independent 32-row groups
// (rows are independent chains in an LSTM). Same columns -> same W tile.
// Per step: one poll + one flag covers 2x work; two groups' coherent h-loads
// pipelined via vmcnt(16)/vmcnt(0). x-part W reloaded from L2 (off critical
// path) to keep VGPR < 256.
// ---------------------------------------------------------------------------
__global__ __launch_bounds__(256, 1) void qlstm_persistent(
    const u16* __restrict__ Xbf,    // [256][128][512] bf16
    u16* __restrict__ hbuf,         // [2][128][512] bf16
    const u16* __restrict__ Wt,     // [2048][1024] bf16, n = j*4+g
    const float* __restrict__ bpn,  // [2048] f32
    float* __restrict__ out,        // [256][128][512] + hx + cx
    unsigned* __restrict__ flags)   // [128]
{
  __shared__ float pre_s[2][32][33];
  const int bid = blockIdx.x;        // 0..127
  const int pair = bid >> 6;         // 0..1 : rows [0,64) or [64,128)
  const int nb = bid & 63;           // col-slice
  const int prow0 = pair * 64;
  const int n0 = nb * 32;
  const int tid = threadIdx.x;
  const int wv = tid >> 6;
  const int lane = tid & 63;
  const int rt = wv >> 1;            // row-tile (16 b's)
  const int nt = wv & 1;             // n-tile (16 cols)
  const int l15 = lane & 15;
  const int kg = lane >> 4;          // k-group 0..3
  const int ncol = n0 + nt * 16 + l15;

  // h-part W (k = 512..1023) register-resident for the whole kernel
  const u16* wrow = Wt + (size_t)ncol * 1024;
  bf16x8 wh[16];
#pragma unroll
  for (int kk = 0; kk < 16; ++kk)
    wh[kk] = *(const bf16x8*)(wrow + 512 + kk * 32 + kg * 8);
  const float bnc = bpn[ncol];

  const int row_in_tile = rt * 16 + l15;     // 0..31 within a group
  const int bb = tid >> 3, jo = tid & 7;
  const size_t eidx0 = (size_t)(prow0 + bb) * 512 + (size_t)(nb * 8 + jo);
  const size_t eidx1 = eidx0 + (size_t)32 * 512;
  float cst0 = 0.f, cst1 = 0.f, hl0 = 0.f, hl1 = 0.f;

  // x-part for t=0 (both groups); wx reloaded from L2 each time
  f32x4 accx0 = {0.f, 0.f, 0.f, 0.f};
  f32x4 accx1 = {0.f, 0.f, 0.f, 0.f};
  {
    const u16* xr0 = Xbf + (size_t)(prow0 + row_in_tile) * 512;
    const u16* xr1 = xr0 + (size_t)32 * 512;
#pragma unroll
    for (int kk = 0; kk < 16; ++kk) {
      bf16x8 wx = *(const bf16x8*)(wrow + kk * 32 + kg * 8);
      bf16x8 xv0 = *(const bf16x8*)(xr0 + kk * 32 + kg * 8);
      bf16x8 xv1 = *(const bf16x8*)(xr1 + kk * 32 + kg * 8);
      accx0 = __builtin_amdgcn_mfma_f32_16x16x32_bf16(xv0, wx, accx0, 0, 0, 0);
      accx1 = __builtin_amdgcn_mfma_f32_16x16x32_bf16(xv1, wx, accx1, 0, 0, 0);
    }
  }

  for (int t = 0; t < 256; ++t) {
    f32x4 acch0 = {0.f, 0.f, 0.f, 0.f};
    f32x4 acch1 = {0.f, 0.f, 0.f, 0.f};
    if (t > 0) {
      if (tid < 64) {                       // wave 0 polls this pair's 64 flags
        const unsigned target = (unsigned)t;
        int guard = 0;
        while (__hip_atomic_load(&flags[pair * 64 + tid], __ATOMIC_RELAXED,
                                 __HIP_MEMORY_SCOPE_AGENT) < target) {
          __builtin_amdgcn_s_sleep(2);
          if (++guard > 30000) break;       // bounded: fail loudly, no hang
        }
      }
      __syncthreads();
      asm volatile("" ::: "memory");

      // ---- pipelined coherent h loads: G0 16, G1 16, vmcnt(16)/vmcnt(0) ----
      const u16* hbase = hbuf + (size_t)((t & 1) ? 65536 : 0);
      const u16* hr0 = hbase + (size_t)(prow0 + row_in_tile) * 512;
      const u16* hr1 = hr0 + (size_t)32 * 512;
      bf16x8 hf0[16], hf1[16];
#pragma unroll
      for (int kk = 0; kk < 16; ++kk)
        ld_llc_b128(hr0 + kk * 32 + kg * 8, hf0[kk]);
#pragma unroll
      for (int kk = 0; kk < 16; ++kk)
        ld_llc_b128(hr1 + kk * 32 + kg * 8, hf1[kk]);
      asm volatile("s_waitcnt vmcnt(16)" ::: "memory");  // G0 ready
      __builtin_amdgcn_sched_barrier(0);
#pragma unroll
      for (int kk = 0; kk < 16; ++kk)
        acch0 = __builtin_amdgcn_mfma_f32_16x16x32_bf16(hf0[kk], wh[kk],
                                                        acch0, 0, 0, 0);
      asm volatile("s_waitcnt vmcnt(0)" ::: "memory");   // G1 ready
      __builtin_amdgcn_sched_barrier(0);
#pragma unroll
      for (int kk = 0; kk < 16; ++kk)
        acch1 = __builtin_amdgcn_mfma_f32_16x16x32_bf16(hf1[kk], wh[kk],
                                                        acch1, 0, 0, 0);
    }

    // C/D layout: col = lane&15, row = (lane>>4)*4 + q
#pragma unroll
    for (int q = 0; q < 4; ++q) {
      pre_s[0][rt * 16 + kg * 4 + q][nt * 16 + l15] = accx0[q] + acch0[q] + bnc;
      pre_s[1][rt * 16 + kg * 4 + q][nt * 16 + l15] = accx1[q] + acch1[q] + bnc;
    }
    __syncthreads();

    // gates + cell update, both groups
    {
      float pf = pre_s[0][bb][jo * 4 + 0];
      float pi = pre_s[0][bb][jo * 4 + 1];
      float pu = pre_s[0][bb][jo * 4 + 2];
      float po = pre_s[0][bb][jo * 4 + 3];
      cst0 = sigm_fast(pf) * cst0 + sigm_fast(pi) * tanh_fast(pu);
      hl0 = sigm_fast(po) * tanh_fast(cst0);
    }
    {
      float pf = pre_s[1][bb][jo * 4 + 0];
      float pi = pre_s[1][bb][jo * 4 + 1];
      float pu = pre_s[1][bb][jo * 4 + 2];
      float po = pre_s[1][bb][jo * 4 + 3];
      cst1 = sigm_fast(pf) * cst1 + sigm_fast(pi) * tanh_fast(pu);
      hl1 = sigm_fast(po) * tanh_fast(cst1);
    }

    // coherent h stores: pack 2 bf16 via shfl, even threads store dwords
    u16* hnext = hbuf + (size_t)(((t + 1) & 1) ? 65536 : 0);
    {
      u16 m0 = f2bf(hl0), m1 = f2bf(hl1);
      u32 p0 = (u32)(u16)__shfl_xor((int)(u32)m0, 1);
      u32 p1 = (u32)(u16)__shfl_xor((int)(u32)m1, 1);
      if ((tid & 1) == 0) {
        st_llc_b32((u32*)(hnext + eidx0), (u32)m0 | (p0 << 16));
        st_llc_b32((u32*)(hnext + eidx1), (u32)m1 | (p1 << 16));
      }
    }
    asm volatile("s_waitcnt vmcnt(0)" ::: "memory");  // asm stores untracked
    __syncthreads();
    if (tid == 0)
      __hip_atomic_store(&flags[bid], (unsigned)(t + 1), __ATOMIC_RELAXED,
                         __HIP_MEMORY_SCOPE_AGENT);

    // off-critical-path: out stores + x-part for t+1
    out[(size_t)t * 65536 + eidx0] = hl0;
    out[(size_t)t * 65536 + eidx1] = hl1;
    if (t < 255) {
      const u16* xr0 = Xbf + (size_t)(t + 1) * 65536 +
                       (size_t)(prow0 + row_in_tile) * 512;
      const u16* xr1 = xr0 + (size_t)32 * 512;
      f32x4 a0 = {0.f, 0.f, 0.f, 0.f};
      f32x4 a1 = {0.f, 0.f, 0.f, 0.f};
#pragma unroll
      for (int kk = 0; kk < 16; ++kk) {
        bf16x8 wx = *(const bf16x8*)(wrow + kk * 32 + kg * 8);
        bf16x8 xv0 = *(const bf16x8*)(xr0 + kk * 32 + kg * 8);
        bf16x8 xv1 = *(const bf16x8*)(xr1 + kk * 32 + kg * 8);
        a0 = __builtin_amdgcn_mfma_f32_16x16x32_bf16(xv0, wx, a0, 0, 0, 0);
        a1 = __builtin_amdgcn_mfma_f32_16x16x32_bf16(xv1, wx, a1, 0, 0, 0);
      }
      accx0 = a0;
      accx1 = a1;
    }
  }

  out[(size_t)256 * 65536 + eidx0] = hl0;
  out[(size_t)256 * 65536 + eidx1] = hl1;
  out[(size_t)256 * 65536 + 65536 + eidx0] = cst0;
  out[(size_t)256 * 65536 + 65536 + eidx1] = cst1;
}

// ---------------------------------------------------------------------------
extern "C" void kernel_launch(void* const* d_in, const int* in_sizes, int n_in,
                              void* d_out, int out_size, void* d_ws, size_t ws_size,
                              hipStream_t stream) {
  (void)in_sizes; (void)n_in; (void)out_size; (void)ws_size;
  const float* inp = (const float*)d_in[0];
  float* out = (float*)d_out;

  char* base = (char*)d_ws;
  u16*      Xbf   = (u16*)base;
  u16*      Wt    = (u16*)(base + 33554432);
  float*    bpn   = (float*)(base + 33554432 + 4194304);
  u16*      hbuf  = (u16*)(base + 33554432 + 4194304 + 8192);
  unsigned* flags = (unsigned*)(base + 33554432 + 4194304 + 8192 + 262144);
  float*    cbuf  = (float*)(base + 33554432 + 4194304 + 8192 + 262144 + 1024);

  const float* W[4];  const float* b[4];  const float* rx[4];  const float* P[4];
  for (int g = 0; g < 4; ++g) {
    W[g]  = (const float*)d_in[1 + 4 * g];
    b[g]  = (const float*)d_in[2 + 4 * g];
    rx[g] = (const float*)d_in[3 + 4 * g];
    P[g]  = (const float*)d_in[4 + 4 * g];
  }
  fold_kernel<<<dim3(16, 8, 4), 256, 0, stream>>>(
      W[0], rx[0], P[0], W[1], rx[1], P[1],
      W[2], rx[2], P[2], W[3], rx[3], P[3], Wt);
  fold_bias<<<dim3(32), 256, 0, stream>>>(
      b[0], rx[0], P[0], b[1], rx[1], P[1],
      b[2], rx[2], P[2], b[3], rx[3], P[3], bpn);
  xcvt_kernel<<<16384, 256, 0, stream>>>(inp, Xbf);
  init_kernel<<<256, 256, 0, stream>>>((unsigned*)hbuf, cbuf, flags);

  void* args[6];
  const u16* Xbf_c = Xbf;
  const u16* Wt_c = Wt;
  const float* bpn_c = bpn;
  u16* hbuf_p = hbuf;
  float* out_p = out;
  unsigned* flags_p = flags;
  args[0] = (void*)&Xbf_c;
  args[1] = (void*)&hbuf_p;
  args[2] = (void*)&Wt_c;
  args[3] = (void*)&bpn_c;
  args[4] = (void*)&out_p;
  args[5] = (void*)&flags_p;
  hipError_t e = hipLaunchCooperativeKernel((const void*)qlstm_persistent,
                                            dim3(128), dim3(256), args, 0, stream);
  if (e != hipSuccess) {
    for (int t = 0; t < 256; ++t) {
      const u16* xb_t  = Xbf + (size_t)t * 65536;
      const u16* h_in  = hbuf + (size_t)(t & 1) * 65536;
      u16*       h_oup = hbuf + (size_t)((t & 1) ^ 1) * 65536;
      float*     out_t = out + (size_t)t * 65536;
      step_kernel<<<256, 256, 0, stream>>>(xb_t, h_in, h_oup, Wt, bpn, cbuf, out_t);
    }
    tail_kernel<<<256, 256, 0, stream>>>(out + (size_t)255 * 65536, cbuf,
                                         out + (size_t)256 * 65536,
                                         out + (size_t)256 * 65536 + 65536);
  }
}

// Round 10
// 1970.488 us; speedup vs baseline: 1.4199x; 1.4199x over previous
//
#include <hip/hip_runtime.h>
#include <hip/hip_bf16.h>

typedef __attribute__((ext_vector_type(8))) short bf16x8;
typedef __attribute__((ext_vector_type(4))) float f32x4;
typedef unsigned short u16;
typedef unsigned int u32;
typedef unsigned long long u64;

__device__ __forceinline__ u16 f2bf(float f) {
  union { float f; unsigned u; } v; v.f = f;
  unsigned r = v.u + 0x7FFFu + ((v.u >> 16) & 1u);   // RTNE
  return (u16)(r >> 16);
}

__device__ __forceinline__ float sigm_fast(float x) {
  return __builtin_amdgcn_rcpf(1.f + __expf(-x));
}
__device__ __forceinline__ float tanh_fast(float x) {
  x = fminf(fmaxf(x, -15.f), 15.f);
  float e = __expf(2.f * x);
  return (e - 1.f) * __builtin_amdgcn_rcpf(e + 1.f);
}

// coherent (LLC) 16B load, untracked by compiler -> caller must waitcnt
__device__ __forceinline__ void ld_llc_b128(const u16* p, bf16x8& r) {
  asm volatile("global_load_dwordx4 %0, %1, off sc0 sc1"
               : "=&v"(r) : "v"(p));
}
// coherent (LLC) 4B store, untracked -> caller must waitcnt before barrier
__device__ __forceinline__ void st_llc_b32(u32* p, u32 v) {
  asm volatile("global_store_dword %0, %1, off sc0 sc1"
               :: "v"(p), "v"(v) : "memory");
}

// ---------------------------------------------------------------------------
// fold (all 4 gates in one dispatch, z = gate):
// Wt[(j*4+g)][k] = sum_m P[m][j] * (W[k][m] * cos(rx[m]))   (bf16 out)
// ---------------------------------------------------------------------------
__global__ __launch_bounds__(256) void fold_kernel(
    const float* __restrict__ W0, const float* __restrict__ rx0, const float* __restrict__ P0,
    const float* __restrict__ W1, const float* __restrict__ rx1, const float* __restrict__ P1,
    const float* __restrict__ W2, const float* __restrict__ rx2, const float* __restrict__ P2,
    const float* __restrict__ W3, const float* __restrict__ rx3, const float* __restrict__ P3,
    u16* __restrict__ Wt)
{
  const int g = blockIdx.z;
  const float* W  = (g == 0) ? W0  : (g == 1) ? W1  : (g == 2) ? W2  : W3;
  const float* rx = (g == 0) ? rx0 : (g == 1) ? rx1 : (g == 2) ? rx2 : rx3;
  const float* P  = (g == 0) ? P0  : (g == 1) ? P1  : (g == 2) ? P2  : P3;
  __shared__ __align__(16) float As[16][68];   // As[m][j]
  __shared__ __align__(16) float Bs[16][68];   // Bs[m][k]
  const int bk = blockIdx.x;   // k-tile 0..15
  const int bj = blockIdx.y;   // j-tile 0..7
  const int tid = threadIdx.x;
  const int tx = tid & 15;     // k-dir
  const int ty = tid >> 4;     // j-dir
  const int j0 = bj * 64, k0 = bk * 64;
  float acc[4][4] = {};
  for (int m0 = 0; m0 < 512; m0 += 16) {
#pragma unroll
    for (int l = 0; l < 4; ++l) {
      int lin = tid + 256 * l;                 // 0..1023
      int mm = lin >> 6, jr = lin & 63;
      As[mm][jr] = P[(m0 + mm) * 512 + j0 + jr];
      int kk = lin >> 4, mb = lin & 15;
      Bs[mb][kk] = W[(k0 + kk) * 512 + m0 + mb] * cosf(rx[m0 + mb]);
    }
    __syncthreads();
#pragma unroll
    for (int mm = 0; mm < 16; ++mm) {
      f32x4 a = *(const f32x4*)&As[mm][ty * 4];
      f32x4 b = *(const f32x4*)&Bs[mm][tx * 4];
#pragma unroll
      for (int i = 0; i < 4; ++i)
#pragma unroll
        for (int jj = 0; jj < 4; ++jj)
          acc[i][jj] += a[i] * b[jj];
    }
    __syncthreads();
  }
#pragma unroll
  for (int i = 0; i < 4; ++i) {
    int j = j0 + ty * 4 + i;
    size_t n = (size_t)(j * 4 + g);
    ushort4 w;
    w.x = f2bf(acc[i][0]); w.y = f2bf(acc[i][1]);
    w.z = f2bf(acc[i][2]); w.w = f2bf(acc[i][3]);
    *(ushort4*)(Wt + n * 1024 + k0 + tx * 4) = w;
  }
}

// bpn[j*4+g] = sum_m b[m]*cos(rx[m])*P[m][j]; grid 32 = 4 gates x 8 j-blocks
__global__ __launch_bounds__(256) void fold_bias(
    const float* __restrict__ b0, const float* __restrict__ rx0, const float* __restrict__ P0,
    const float* __restrict__ b1, const float* __restrict__ rx1, const float* __restrict__ P1,
    const float* __restrict__ b2, const float* __restrict__ rx2, const float* __restrict__ P2,
    const float* __restrict__ b3, const float* __restrict__ rx3, const float* __restrict__ P3,
    float* __restrict__ bpn)
{
  const int g = blockIdx.x >> 3, jb = blockIdx.x & 7;
  const float* b  = (g == 0) ? b0  : (g == 1) ? b1  : (g == 2) ? b2  : b3;
  const float* rx = (g == 0) ? rx0 : (g == 1) ? rx1 : (g == 2) ? rx2 : rx3;
  const float* P  = (g == 0) ? P0  : (g == 1) ? P1  : (g == 2) ? P2  : P3;
  __shared__ float bc[512];
  __shared__ float red[4][65];
  const int tid = threadIdx.x;
  bc[tid] = b[tid] * cosf(rx[tid]);
  bc[tid + 256] = b[tid + 256] * cosf(rx[tid + 256]);
  __syncthreads();
  const int jl = tid & 63, msub = tid >> 6;
  const int j = jb * 64 + jl;
  float acc = 0.f;
  for (int m = msub * 128; m < msub * 128 + 128; ++m)
    acc += bc[m] * P[m * 512 + j];
  red[msub][jl] = acc;
  __syncthreads();
  if (msub == 0)
    bpn[j * 4 + g] = red[0][jl] + red[1][jl] + red[2][jl] + red[3][jl];
}

// convert whole input X (T*B*D f32) to bf16 once
__global__ __launch_bounds__(256) void xcvt_kernel(
    const float* __restrict__ x, u16* __restrict__ xb)
{
  size_t i = (size_t)blockIdx.x * 256 + threadIdx.x;  // group of 4 elems
  f32x4 v = *(const f32x4*)(x + i * 4);
  ushort4 w;
  w.x = f2bf(v[0]); w.y = f2bf(v[1]); w.z = f2bf(v[2]); w.w = f2bf(v[3]);
  *(ushort4*)(xb + i * 4) = w;
}

// zero hbuf (both parities) + cbuf + flags, every launch (replay determinism)
__global__ __launch_bounds__(256) void init_kernel(unsigned* hbuf32, float* cbuf,
                                                   unsigned* flags) {
  int i = blockIdx.x * 256 + threadIdx.x;      // 65536
  hbuf32[i] = 0;
  cbuf[i] = 0.f;
  if (i < 256) flags[i] = 0;
}

__global__ __launch_bounds__(256) void tail_kernel(
    const float* __restrict__ hlast, const float* __restrict__ c,
    float* __restrict__ hx, float* __restrict__ cx)
{
  int i = blockIdx.x * 256 + threadIdx.x;      // 65536
  hx[i] = hlast[i];
  cx[i] = c[i];
}

// ---------------------------------------------------------------------------
// fallback single-step kernel (R1-proven)
// ---------------------------------------------------------------------------
__global__ __launch_bounds__(256) void step_kernel(
    const u16* __restrict__ xb_t, const u16* __restrict__ h_in,
    u16* __restrict__ h_out, const u16* __restrict__ Wt,
    const float* __restrict__ bpn, float* __restrict__ cbuf,
    float* __restrict__ out_t)
{
  __shared__ float pre_s[32][33];
  const int bid = blockIdx.x;
  const int mb = bid >> 6, nb = bid & 63;
  const int b0 = mb * 32, n0 = nb * 32;
  const int tid = threadIdx.x;
  const int wv = tid >> 6, lane = tid & 63;
  const int rt = wv >> 1, nt = wv & 1;
  const int l15 = lane & 15, kg = lane >> 4;
  const int brow = b0 + rt * 16 + l15;
  const int ncol = n0 + nt * 16 + l15;
  const u16* wrow = Wt + (size_t)ncol * 1024;
  const u16* xrow = xb_t + (size_t)brow * 512;
  const u16* hrow = h_in + (size_t)brow * 512;
  f32x4 acc = {0.f, 0.f, 0.f, 0.f};
#pragma unroll 8
  for (int kk = 0; kk < 32; ++kk) {
    const int kb = kk * 32 + kg * 8;
    bf16x8 bfrag = *(const bf16x8*)(wrow + kb);
    bf16x8 afrag;
    if (kb < 512) afrag = *(const bf16x8*)(xrow + kb);
    else          afrag = *(const bf16x8*)(hrow + (kb - 512));
    acc = __builtin_amdgcn_mfma_f32_16x16x32_bf16(afrag, bfrag, acc, 0, 0, 0);
  }
  const float bias = bpn[ncol];
#pragma unroll
  for (int q = 0; q < 4; ++q)
    pre_s[rt * 16 + kg * 4 + q][nt * 16 + l15] = acc[q] + bias;
  __syncthreads();
  const int bb = tid >> 3, jo = tid & 7;
  float pf = pre_s[bb][jo * 4 + 0];
  float pi = pre_s[bb][jo * 4 + 1];
  float pu = pre_s[bb][jo * 4 + 2];
  float po = pre_s[bb][jo * 4 + 3];
  float fg = 1.f / (1.f + __expf(-pf));
  float ig = 1.f / (1.f + __expf(-pi));
  float gg = tanhf(pu);
  float og = 1.f / (1.f + __expf(-po));
  size_t idx = (size_t)(b0 + bb) * 512 + (size_t)(nb * 8 + jo);
  float cv = fg * cbuf[idx] + ig * gg;
  cbuf[idx] = cv;
  float hv = og * tanhf(cv);
  out_t[idx] = hv;
  h_out[idx] = f2bf(hv);
}

// ---------------------------------------------------------------------------
// persistent recurrence v4: 256 wgs x 512 threads (2 waves/SIMD).
// Wave specialization: waves 0-3 = h-GEMM (critical chain), waves 4-7 =
// x-GEMM from prefetched registers + prefetch x(t+1) (off critical path).
// Raw s_barrier + counted waits: x prefetch loads stay in flight across
// barriers; only LDS producers drain lgkmcnt, only h-stores drain vmcnt.
// Every h-wave polls the 64 group flags itself (no barrier between poll
// and h-loads).
// ---------------------------------------------------------------------------
__global__ __launch_bounds__(512, 2) void qlstm_persistent(
    const u16* __restrict__ Xbf,    // [256][128][512] bf16
    u16* __restrict__ hbuf,         // [2][128][512] bf16
    const u16* __restrict__ Wt,     // [2048][1024] bf16, n = j*4+g
    const float* __restrict__ bpn,  // [2048] f32
    float* __restrict__ out,        // [256][128][512] + hx + cx
    unsigned* __restrict__ flags)   // [256]
{
  __shared__ float pre_h[32][33];
  __shared__ float pre_x[32][33];
  const int bid = blockIdx.x;        // 0..255
  const int mb = bid >> 6;           // 0..3
  const int nb = bid & 63;           // 0..63
  const int tid = threadIdx.x;       // 0..511
  const int wv = tid >> 6;           // 0..7
  const int lane = tid & 63;
  const bool is_h = (wv < 4);
  const int sub = wv & 3;
  const int rt = sub >> 1;           // row-tile (16 b's)
  const int nt = sub & 1;            // n-tile (16 cols)
  const int l15 = lane & 15;
  const int kg = lane >> 4;          // k-group 0..3
  const int brow = mb * 32 + rt * 16 + l15;
  const int ncol = nb * 32 + nt * 16 + l15;
  const u16* wrow = Wt + (size_t)ncol * 1024;

  // role-specific W half -> registers (h: k=512..1023, x: k=0..511)
  bf16x8 wreg[16];
  {
    const u16* wsrc = wrow + (is_h ? 512 : 0);
#pragma unroll
    for (int kk = 0; kk < 16; ++kk)
      wreg[kk] = *(const bf16x8*)(wsrc + kk * 32 + kg * 8);
  }
  const float bnc = bpn[ncol];

  const int bb = (tid & 255) >> 3, jo = tid & 7;
  const size_t eidx = (size_t)(mb * 32 + bb) * 512 + (size_t)(nb * 8 + jo);
  float cst = 0.f, hlast = 0.f;

  // x prologue: prefetch xfrag for t=0 (plain loads, compiler-tracked)
  bf16x8 xfrag[16];
  if (!is_h) {
    const u16* xr = Xbf + (size_t)brow * 512;
#pragma unroll
    for (int kk = 0; kk < 16; ++kk)
      xfrag[kk] = *(const bf16x8*)(xr + kk * 32 + kg * 8);
  }

  for (int t = 0; t < 256; ++t) {
    if (!is_h) {
      // ---- x-GEMM for step t from prefetched registers ----
      f32x4 ax = {0.f, 0.f, 0.f, 0.f};
#pragma unroll
      for (int kk = 0; kk < 16; ++kk)
        ax = __builtin_amdgcn_mfma_f32_16x16x32_bf16(xfrag[kk], wreg[kk],
                                                     ax, 0, 0, 0);
#pragma unroll
      for (int q = 0; q < 4; ++q)
        pre_x[rt * 16 + kg * 4 + q][nt * 16 + l15] = ax[q] + bnc;
      // prefetch x(t+1); loads stay in flight across the barriers
      if (t < 255) {
        const u16* xr = Xbf + (size_t)(t + 1) * 65536 + (size_t)brow * 512;
#pragma unroll
        for (int kk = 0; kk < 16; ++kk)
          xfrag[kk] = *(const bf16x8*)(xr + kk * 32 + kg * 8);
      }
      asm volatile("s_waitcnt lgkmcnt(0)" ::: "memory");  // pre_x committed
    } else {
      // ---- h-GEMM (critical chain) ----
      f32x4 ah = {0.f, 0.f, 0.f, 0.f};
      if (t > 0) {
        const unsigned target = (unsigned)t;        // every h-wave polls
        int guard = 0;
        while (__hip_atomic_load(&flags[mb * 64 + lane], __ATOMIC_RELAXED,
                                 __HIP_MEMORY_SCOPE_AGENT) < target) {
          __builtin_amdgcn_s_sleep(1);
          if (++guard > 30000) break;               // bounded: fail loudly
        }
        asm volatile("" ::: "memory");
        const u16* hr = hbuf + (size_t)((t & 1) ? 65536 : 0)
                        + (size_t)brow * 512;
        bf16x8 hf[16];
#pragma unroll
        for (int kk = 0; kk < 16; ++kk)
          ld_llc_b128(hr + kk * 32 + kg * 8, hf[kk]);
        asm volatile("s_waitcnt vmcnt(0)" ::: "memory");
        __builtin_amdgcn_sched_barrier(0);          // keep MFMAs below wait
#pragma unroll
        for (int kk = 0; kk < 16; ++kk)
          ah = __builtin_amdgcn_mfma_f32_16x16x32_bf16(hf[kk], wreg[kk],
                                                       ah, 0, 0, 0);
      }
#pragma unroll
      for (int q = 0; q < 4; ++q)
        pre_h[rt * 16 + kg * 4 + q][nt * 16 + l15] = ah[q];
      asm volatile("s_waitcnt lgkmcnt(0)" ::: "memory");  // pre_h committed
    }
    __builtin_amdgcn_s_barrier();                   // B: pre ready
    asm volatile("" ::: "memory");

    if (tid < 256) {
      float pf = pre_h[bb][jo * 4 + 0] + pre_x[bb][jo * 4 + 0];
      float pi = pre_h[bb][jo * 4 + 1] + pre_x[bb][jo * 4 + 1];
      float pu = pre_h[bb][jo * 4 + 2] + pre_x[bb][jo * 4 + 2];
      float po = pre_h[bb][jo * 4 + 3] + pre_x[bb][jo * 4 + 3];
      cst = sigm_fast(pf) * cst + sigm_fast(pi) * tanh_fast(pu);
      float hv = sigm_fast(po) * tanh_fast(cst);
      hlast = hv;
      u16 myh = f2bf(hv);
      u32 partner = (u32)(u16)__shfl_xor((int)(u32)myh, 1);
      u16* hnext = hbuf + (size_t)(((t + 1) & 1) ? 65536 : 0);
      if ((tid & 1) == 0)
        st_llc_b32((u32*)(hnext + eidx), (u32)myh | (partner << 16));
      asm volatile("s_waitcnt vmcnt(0)" ::: "memory");  // h-stores drained
    }
    __builtin_amdgcn_s_barrier();                   // C
    asm volatile("" ::: "memory");
    if (tid == 0)
      __hip_atomic_store(&flags[bid], (unsigned)(t + 1), __ATOMIC_RELAXED,
                         __HIP_MEMORY_SCOPE_AGENT);
    if (tid < 256)
      out[(size_t)t * 65536 + eidx] = hlast;        // off critical path
  }

  if (tid < 256) {
    out[(size_t)256 * 65536 + eidx] = hlast;
    out[(size_t)256 * 65536 + 65536 + eidx] = cst;
  }
}

// ---------------------------------------------------------------------------
extern "C" void kernel_launch(void* const* d_in, const int* in_sizes, int n_in,
                              void* d_out, int out_size, void* d_ws, size_t ws_size,
                              hipStream_t stream) {
  (void)in_sizes; (void)n_in; (void)out_size; (void)ws_size;
  const float* inp = (const float*)d_in[0];
  float* out = (float*)d_out;

  char* base = (char*)d_ws;
  u16*      Xbf   = (u16*)base;
  u16*      Wt    = (u16*)(base + 33554432);
  float*    bpn   = (float*)(base + 33554432 + 4194304);
  u16*      hbuf  = (u16*)(base + 33554432 + 4194304 + 8192);
  unsigned* flags = (unsigned*)(base + 33554432 + 4194304 + 8192 + 262144);
  float*    cbuf  = (float*)(base + 33554432 + 4194304 + 8192 + 262144 + 1024);

  const float* W[4];  const float* b[4];  const float* rx[4];  const float* P[4];
  for (int g = 0; g < 4; ++g) {
    W[g]  = (const float*)d_in[1 + 4 * g];
    b[g]  = (const float*)d_in[2 + 4 * g];
    rx[g] = (const float*)d_in[3 + 4 * g];
    P[g]  = (const float*)d_in[4 + 4 * g];
  }
  fold_kernel<<<dim3(16, 8, 4), 256, 0, stream>>>(
      W[0], rx[0], P[0], W[1], rx[1], P[1],
      W[2], rx[2], P[2], W[3], rx[3], P[3], Wt);
  fold_bias<<<dim3(32), 256, 0, stream>>>(
      b[0], rx[0], P[0], b[1], rx[1], P[1],
      b[2], rx[2], P[2], b[3], rx[3], P[3], bpn);
  xcvt_kernel<<<16384, 256, 0, stream>>>(inp, Xbf);
  init_kernel<<<256, 256, 0, stream>>>((unsigned*)hbuf, cbuf, flags);

  void* args[6];
  const u16* Xbf_c = Xbf;
  const u16* Wt_c = Wt;
  const float* bpn_c = bpn;
  u16* hbuf_p = hbuf;
  float* out_p = out;
  unsigned* flags_p = flags;
  args[0] = (void*)&Xbf_c;
  args[1] = (void*)&hbuf_p;
  args[2] = (void*)&Wt_c;
  args[3] = (void*)&bpn_c;
  args[4] = (void*)&out_p;
  args[5] = (void*)&flags_p;
  hipError_t e = hipLaunchCooperativeKernel((const void*)qlstm_persistent,
                                            dim3(256), dim3(512), args, 0, stream);
  if (e != hipSuccess) {
    for (int t = 0; t < 256; ++t) {
      const u16* xb_t  = Xbf + (size_t)t * 65536;
      const u16* h_in  = hbuf + (size_t)(t & 1) * 65536;
      u16*       h_oup = hbuf + (size_t)((t & 1) ^ 1) * 65536;
      float*     out_t = out + (size_t)t * 65536;
      step_kernel<<<256, 256, 0, stream>>>(xb_t, h_in, h_oup, Wt, bpn, cbuf, out_t);
    }
    tail_kernel<<<256, 256, 0, stream>>>(out + (size_t)255 * 65536, cbuf,
                                         out + (size_t)256 * 65536,
                                         out + (size_t)256 * 65536 + 65536);
  }
}